// Round 1
// baseline (361.558 us; speedup 1.0000x reference)
//
#include <hip/hip_runtime.h>
#include <hip/hip_bf16.h>
#include <stdint.h>

#define IN_CH 128
#define NPB   448            // nodes per bucket
#define NBUCK 224            // NBUCK*NPB = 100352 >= N
#define CAP   8192           // edge capacity per bucket region (avg ~7150)
#define PART_EPB 2048        // edges per partition block (8KB LDS tile, 782 blocks)
#define SRC_BITS 17          // src < 131072
#define SRC_MASK ((1 << SRC_BITS) - 1)

typedef short v8s __attribute__((ext_vector_type(8)));
typedef float v4f __attribute__((ext_vector_type(4)));
typedef ushort v4u __attribute__((ext_vector_type(4)));

__device__ __forceinline__ ushort f2b(float f) {
    return ((__hip_bfloat16_raw)__float2bfloat16(f)).x;
}
__device__ __forceinline__ float b2f(ushort u) {
    __hip_bfloat16_raw r; r.x = u;
    return __bfloat162float((__hip_bfloat16)r);
}

// ---------------------------------- coalesced radix partition of edges by dst
// Fixed per-bucket regions ebuf[b*CAP ..]; global cursor[b] tracks fill.
__global__ __launch_bounds__(256) void k_part(
    const int* __restrict__ src, const int* __restrict__ dst,
    int* __restrict__ cursor, int* __restrict__ ebuf, int E) {
    __shared__ int sedge[PART_EPB];                    // 8 KB
    __shared__ int h[NBUCK], lofs[NBUCK], gbase[NBUCK], lcur[NBUCK];
    __shared__ int ssc[256];

    int tid = threadIdx.x;
    int eb0 = blockIdx.x * PART_EPB;
    int cnt = min(PART_EPB, E - eb0);

    if (tid < NBUCK) { h[tid] = 0; lcur[tid] = 0; }
    __syncthreads();
    for (int i = tid; i < cnt; i += 256)
        atomicAdd(&h[dst[eb0 + i] / NPB], 1);
    __syncthreads();
    int v = (tid < NBUCK) ? h[tid] : 0;
    ssc[tid] = v;
    __syncthreads();
    for (int off = 1; off < 256; off <<= 1) {
        int val = (tid >= off) ? ssc[tid - off] : 0;
        __syncthreads();
        ssc[tid] += val;
        __syncthreads();
    }
    int excl = ssc[tid] - v;
    if (tid < NBUCK) {
        lofs[tid] = excl;
        gbase[tid] = tid * CAP + atomicAdd(&cursor[tid], v);
    }
    __syncthreads();
    for (int i = tid; i < cnt; i += 256) {
        int s0 = src[eb0 + i];
        int d0 = dst[eb0 + i];
        int b = d0 / NPB;
        int dl = d0 - b * NPB;
        int p = atomicAdd(&lcur[b], 1);
        sedge[lofs[b] + p] = (dl << SRC_BITS) | s0;
    }
    __syncthreads();
    // contiguous run writes; recover bucket by binary search over lofs
    for (int i = tid; i < cnt; i += 256) {
        int lo = 0, hi = NBUCK - 1;
        while (lo < hi) {
            int mid = (lo + hi + 1) >> 1;
            if (lofs[mid] <= i) lo = mid; else hi = mid - 1;
        }
        int pos = gbase[lo] + (i - lofs[lo]);
        if (pos < (lo + 1) * CAP) ebuf[pos] = sedge[i];  // overflow guard
    }
}

// ---------------------- per-bucket CSR build: hist -> scan -> scatter, L2-local
__global__ __launch_bounds__(256) void k_bbuild(
    const int* __restrict__ ebuf, const int* __restrict__ cursor,
    int* __restrict__ row_ptr, int* __restrict__ deg,
    int* __restrict__ col, int N) {
    __shared__ int sdeg[NPB];
    __shared__ int scur[NPB];
    __shared__ int ssum[256];
    int b = blockIdx.x, tid = threadIdx.x;
    int base = b * NPB;
    int nodes = min(NPB, N - base);
    int e0 = b * CAP;
    int e1 = e0 + min(cursor[b], CAP);

    for (int i = tid; i < NPB; i += 256) sdeg[i] = 0;
    __syncthreads();
    for (int e = e0 + tid; e < e1; e += 256)
        atomicAdd(&sdeg[((unsigned)ebuf[e]) >> SRC_BITS], 1);
    __syncthreads();
    int d0 = 0, d1 = 0;
    if (tid < 224) { d0 = sdeg[2 * tid]; d1 = sdeg[2 * tid + 1]; }
    int ts = d0 + d1;
    ssum[tid] = ts;
    __syncthreads();
    for (int off = 1; off < 256; off <<= 1) {
        int val = (tid >= off) ? ssum[tid - off] : 0;
        __syncthreads();
        ssum[tid] += val;
        __syncthreads();
    }
    int excl = ssum[tid] - ts;
    if (tid < 224) {
        scur[2 * tid] = excl;
        scur[2 * tid + 1] = excl + d0;
        if (2 * tid < nodes) {
            row_ptr[base + 2 * tid] = e0 + excl;
            deg[base + 2 * tid] = d0;
        }
        if (2 * tid + 1 < nodes) {
            row_ptr[base + 2 * tid + 1] = e0 + excl + d0;
            deg[base + 2 * tid + 1] = d1;
        }
    }
    __syncthreads();
    for (int e = e0 + tid; e < e1; e += 256) {
        int w = ebuf[e];
        int dl = ((unsigned)w) >> SRC_BITS;
        int p = atomicAdd(&scur[dl], 1);
        col[e0 + p] = w & SRC_MASK;
    }
}

// ------------------------------------------------- MFMA GEMM, W in LDS
// MODE 0 (layer 1): A = x fp32 [N][128] (converted in-register), OC=256,
//                   c<128 -> q1b[N][128] bf16, c>=128 -> p1b[N][128] bf16
// MODE 1 (layer 2): A = hb bf16 [N][128], OC=128,
//                   c<64 -> q2[N][64] bf16, c>=64 -> p2[N][64] fp32
// W staged into LDS from fp32 Wl/Wr (cast fused). Row pad +8 shorts.
template <int OC, int MODE>
__global__ __launch_bounds__(256) void k_wgemm(
    const float* __restrict__ Af, const ushort* __restrict__ Ab,
    const float* __restrict__ WlF, const float* __restrict__ WrF,
    ushort* __restrict__ qb, ushort* __restrict__ pbb, float* __restrict__ pbf,
    int N) {
    const int NT = OC / 16;
    const int LDW = 128 + 8;
    __shared__ ushort Wlds[OC * LDW];

    int tid = threadIdx.x;
    // stage + cast W: OC rows x 128 k, 8 floats per thread-chunk
    for (int it = 0; it < OC / 16; it++) {
        int idx = it * 256 + tid;
        int r = idx >> 4, kc = (idx & 15) * 8;
        const float* Wrow = (r < OC / 2) ? (WlF + (size_t)r * 128)
                                         : (WrF + (size_t)(r - OC / 2) * 128);
        float4 w0 = *(const float4*)(Wrow + kc);
        float4 w1 = *(const float4*)(Wrow + kc + 4);
        v8s wv;
        wv[0] = (short)f2b(w0.x); wv[1] = (short)f2b(w0.y);
        wv[2] = (short)f2b(w0.z); wv[3] = (short)f2b(w0.w);
        wv[4] = (short)f2b(w1.x); wv[5] = (short)f2b(w1.y);
        wv[6] = (short)f2b(w1.z); wv[7] = (short)f2b(w1.w);
        *(v8s*)((short*)Wlds + r * LDW + kc) = wv;
    }
    __syncthreads();

    int wave = tid >> 6;
    int lane = tid & 63;
    int m16 = lane & 15;
    int quad = lane >> 4;
    int rowbase = blockIdx.x * 128 + wave * 32;

    v4f acc[2][NT];
#pragma unroll
    for (int mt = 0; mt < 2; mt++)
#pragma unroll
        for (int t = 0; t < NT; t++) acc[mt][t] = {0.f, 0.f, 0.f, 0.f};

    int ar0 = min(rowbase + m16, N - 1);
    int ar1 = min(rowbase + 16 + m16, N - 1);

#pragma unroll
    for (int ks = 0; ks < 4; ks++) {
        int k0 = ks * 32 + quad * 8;
        v8s a0, a1;
        if (MODE == 0) {
            float4 f00 = *(const float4*)(Af + (size_t)ar0 * 128 + k0);
            float4 f01 = *(const float4*)(Af + (size_t)ar0 * 128 + k0 + 4);
            float4 f10 = *(const float4*)(Af + (size_t)ar1 * 128 + k0);
            float4 f11 = *(const float4*)(Af + (size_t)ar1 * 128 + k0 + 4);
            a0[0] = (short)f2b(f00.x); a0[1] = (short)f2b(f00.y);
            a0[2] = (short)f2b(f00.z); a0[3] = (short)f2b(f00.w);
            a0[4] = (short)f2b(f01.x); a0[5] = (short)f2b(f01.y);
            a0[6] = (short)f2b(f01.z); a0[7] = (short)f2b(f01.w);
            a1[0] = (short)f2b(f10.x); a1[1] = (short)f2b(f10.y);
            a1[2] = (short)f2b(f10.z); a1[3] = (short)f2b(f10.w);
            a1[4] = (short)f2b(f11.x); a1[5] = (short)f2b(f11.y);
            a1[6] = (short)f2b(f11.z); a1[7] = (short)f2b(f11.w);
        } else {
            a0 = *(const v8s*)((const short*)Ab + (size_t)ar0 * 128 + k0);
            a1 = *(const v8s*)((const short*)Ab + (size_t)ar1 * 128 + k0);
        }
#pragma unroll
        for (int t = 0; t < NT; t++) {
            v8s b = *(const v8s*)((const short*)Wlds + (t * 16 + m16) * LDW + k0);
            acc[0][t] = __builtin_amdgcn_mfma_f32_16x16x32_bf16(a0, b, acc[0][t], 0, 0, 0);
            acc[1][t] = __builtin_amdgcn_mfma_f32_16x16x32_bf16(a1, b, acc[1][t], 0, 0, 0);
        }
    }

    // C/D layout: col = t*16 + m16, row(within tile) = quad*4 + r
#pragma unroll
    for (int mt = 0; mt < 2; mt++) {
        int orow0 = rowbase + mt * 16 + quad * 4;
#pragma unroll
        for (int r = 0; r < 4; r++) {
            int orow = orow0 + r;
            if (orow < N) {
#pragma unroll
                for (int t = 0; t < NT; t++) {
                    int c = t * 16 + m16;
                    float v = acc[mt][t][r];
                    if (MODE == 0) {
                        if (c < 128) qb[(size_t)orow * 128 + c] = f2b(v);
                        else pbb[(size_t)orow * 128 + (c - 128)] = f2b(v);
                    } else {
                        if (c < 64) qb[(size_t)orow * 64 + c] = f2b(v);
                        else pbf[(size_t)orow * 64 + (c - 64)] = v;
                    }
                }
            }
        }
    }
}

// ------------------- layer-1 aggregation: h = ReLU(mean(Q1) + P1 + b1) -> bf16
// q1b[N][128], p1b[N][128] bf16. 1 wave/node; two 32-lane halves, each lane
// loads ushort4 (8B) -> one 256B row per half per slot; 8-deep unroll
// => 16 rows in flight/wave. Tail handled by clamped index + predicated add
// (keeps full MLP on the last partial iteration). shfl_xor(32) combines halves.
__global__ void k_agg1(const int* __restrict__ row_ptr, const int* __restrict__ deg,
                       const int* __restrict__ col, const ushort* __restrict__ q1b,
                       const ushort* __restrict__ p1b, const float* __restrict__ bias,
                       ushort* __restrict__ hb, int N) {
    int node = blockIdx.x * (blockDim.x >> 6) + (threadIdx.x >> 6);
    int lane = threadIdx.x & 63;
    if (node >= N) return;
    int s0 = row_ptr[node];
    int dn = deg[node];
    int s1 = s0 + dn;
    int half = lane >> 5, cl = lane & 31;
    int ch = 4 * cl;                        // 4 channels per lane, 8B loads
    float a0 = 0.f, a1 = 0.f, a2 = 0.f, a3 = 0.f;
    for (int j = s0; j < s1; j += 16) {
#pragma unroll
        for (int t = 0; t < 8; t++) {
            int idx = j + 2 * t + half;
            int c = col[min(idx, s1 - 1)];
            v4u v = *(const v4u*)(q1b + (size_t)c * 128 + ch);
            if (idx < s1) {
                a0 += b2f(v.x); a1 += b2f(v.y);
                a2 += b2f(v.z); a3 += b2f(v.w);
            }
        }
    }
    a0 += __shfl_xor(a0, 32);
    a1 += __shfl_xor(a1, 32);
    a2 += __shfl_xor(a2, 32);
    a3 += __shfl_xor(a3, 32);
    if (half == 0) {
        float inv = (dn > 0) ? 1.0f / (float)dn : 0.0f;
        v4u pb = __builtin_nontemporal_load((const v4u*)(p1b + (size_t)node * 128 + ch));
        float4 bi = *(const float4*)(bias + ch);
        v4u o;
        o.x = f2b(fmaxf(a0 * inv + b2f(pb.x) + bi.x, 0.f));
        o.y = f2b(fmaxf(a1 * inv + b2f(pb.y) + bi.y, 0.f));
        o.z = f2b(fmaxf(a2 * inv + b2f(pb.z) + bi.z, 0.f));
        o.w = f2b(fmaxf(a3 * inv + b2f(pb.w) + bi.w, 0.f));
        __builtin_nontemporal_store(o, (v4u*)(hb + (size_t)node * 128 + ch));
    }
}

// ------------------- layer-2 aggregation: out = mean(Q2) + P2 + b2 -> fp32
// q2[N][64] bf16 (128B rows), p2[N][64] fp32. 1 wave/node; four 16-lane
// groups, each lane loads ushort4 (8B) -> one 128B row per group per slot;
// 8-deep unroll => 32 rows in flight/wave. Clamped-index masked tail.
// shfl_xor(16)+shfl_xor(32) combine groups.
__global__ void k_agg2(const int* __restrict__ row_ptr, const int* __restrict__ deg,
                       const int* __restrict__ col, const ushort* __restrict__ q2,
                       const float* __restrict__ p2, const float* __restrict__ bias,
                       float* __restrict__ out, int N) {
    int node = blockIdx.x * (blockDim.x >> 6) + (threadIdx.x >> 6);
    int lane = threadIdx.x & 63;
    if (node >= N) return;
    int s0 = row_ptr[node];
    int dn = deg[node];
    int s1 = s0 + dn;
    int g = lane >> 4, cl = lane & 15;
    int ch = 4 * cl;                        // 4 channels per lane, 8B loads
    float a0 = 0.f, a1 = 0.f, a2 = 0.f, a3 = 0.f;
    for (int j = s0; j < s1; j += 32) {
#pragma unroll
        for (int t = 0; t < 8; t++) {
            int idx = j + 4 * t + g;
            int c = col[min(idx, s1 - 1)];
            v4u v = *(const v4u*)(q2 + (size_t)c * 64 + ch);
            if (idx < s1) {
                a0 += b2f(v.x); a1 += b2f(v.y);
                a2 += b2f(v.z); a3 += b2f(v.w);
            }
        }
    }
    a0 += __shfl_xor(a0, 16);
    a1 += __shfl_xor(a1, 16);
    a2 += __shfl_xor(a2, 16);
    a3 += __shfl_xor(a3, 16);
    a0 += __shfl_xor(a0, 32);
    a1 += __shfl_xor(a1, 32);
    a2 += __shfl_xor(a2, 32);
    a3 += __shfl_xor(a3, 32);
    if (lane < 16) {
        float inv = (dn > 0) ? 1.0f / (float)dn : 0.0f;
        v4f pv = __builtin_nontemporal_load((const v4f*)(p2 + (size_t)node * 64 + ch));
        float4 bi = *(const float4*)(bias + ch);
        v4f o;
        o[0] = a0 * inv + pv[0] + bi.x;
        o[1] = a1 * inv + pv[1] + bi.y;
        o[2] = a2 * inv + pv[2] + bi.z;
        o[3] = a3 * inv + pv[3] + bi.w;
        __builtin_nontemporal_store(o, (v4f*)(out + (size_t)node * 64 + ch));
    }
}

extern "C" void kernel_launch(void* const* d_in, const int* in_sizes, int n_in,
                              void* d_out, int out_size, void* d_ws, size_t ws_size,
                              hipStream_t stream) {
    const float* x   = (const float*)d_in[0];
    const int* ei    = (const int*)d_in[1];
    const float* Wl1 = (const float*)d_in[2];
    const float* bl1 = (const float*)d_in[3];
    const float* Wr1 = (const float*)d_in[4];
    const float* Wl2 = (const float*)d_in[5];
    const float* bl2 = (const float*)d_in[6];
    const float* Wr2 = (const float*)d_in[7];

    const int N = in_sizes[0] / IN_CH;   // 100000
    const int E = in_sizes[1] / 2;       // 1600000
    const int* src = ei;
    const int* dst = ei + E;

    char* p = (char*)d_ws;
    auto carve = [&](size_t bytes) -> void* {
        void* q = (void*)p;
        p += (bytes + 255) & ~(size_t)255;
        return q;
    };
    int* cursor   = (int*)carve(NBUCK * 4);
    int* ebuf     = (int*)carve((size_t)NBUCK * CAP * 4);
    int* col      = (int*)carve((size_t)NBUCK * CAP * 4);
    int* row_ptr  = (int*)carve((size_t)N * 4);
    int* deg      = (int*)carve((size_t)N * 4);
    ushort* q1b   = (ushort*)carve((size_t)N * 128 * 2);
    ushort* p1b   = (ushort*)carve((size_t)N * 128 * 2);
    ushort* hb    = (ushort*)carve((size_t)N * 128 * 2);
    ushort* q2    = (ushort*)carve((size_t)N * 64 * 2);
    float* p2     = (float*)carve((size_t)N * 64 * 4);
    (void)ws_size; (void)n_in;

    float* out = (float*)d_out;
    (void)out_size;

    // ---- partition + CSR build ----
    (void)hipMemsetAsync(cursor, 0, NBUCK * 4, stream);
    k_part<<<(E + PART_EPB - 1) / PART_EPB, 256, 0, stream>>>(src, dst, cursor, ebuf, E);
    k_bbuild<<<NBUCK, 256, 0, stream>>>(ebuf, cursor, row_ptr, deg, col, N);

    // ---- layer 1: [Q1|P1] = x @ [Wl1;Wr1].T (fp32 A, fused cast);
    //      h = ReLU(mean(Q1)+P1+b1) ----
    k_wgemm<256, 0><<<(N + 127) / 128, 256, 0, stream>>>(
        x, nullptr, Wl1, Wr1, q1b, p1b, nullptr, N);
    k_agg1<<<(N + 3) / 4, 256, 0, stream>>>(row_ptr, deg, col, q1b, p1b, bl1, hb, N);

    // ---- layer 2: [Q2|P2] = hb @ [Wl2;Wr2].T; out = mean(Q2)+P2+b2 ----
    k_wgemm<128, 1><<<(N + 127) / 128, 256, 0, stream>>>(
        nullptr, hb, Wl2, Wr2, q2, nullptr, p2, N);
    k_agg2<<<(N + 3) / 4, 256, 0, stream>>>(row_ptr, deg, col, q2, p2, bl2, out, N);
}

// Round 3
// 300.050 us; speedup vs baseline: 1.2050x; 1.2050x over previous
//
#include <hip/hip_runtime.h>
#include <hip/hip_bf16.h>
#include <stdint.h>

#define IN_CH 128
#define NPB   448            // nodes per bucket
#define NBUCK 224            // NBUCK*NPB = 100352 >= N
#define CAP   8192           // edge capacity per bucket region (avg ~7150)
#define PART_EPB 2048        // edges per partition block (8KB LDS tile, 782 blocks)
#define SRC_BITS 17          // src < 131072
#define SRC_MASK ((1 << SRC_BITS) - 1)

typedef short v8s __attribute__((ext_vector_type(8)));
typedef float v4f __attribute__((ext_vector_type(4)));
typedef float v2f __attribute__((ext_vector_type(2)));
typedef ushort v4u __attribute__((ext_vector_type(4)));

__device__ __forceinline__ ushort f2b(float f) {
    return ((__hip_bfloat16_raw)__float2bfloat16(f)).x;
}
__device__ __forceinline__ float b2f(ushort u) {
    __hip_bfloat16_raw r; r.x = u;
    return __bfloat162float((__hip_bfloat16)r);
}

// ---------------------------------- coalesced radix partition of edges by dst
// Fixed per-bucket regions ebuf[b*CAP ..]; global cursor[b] tracks fill.
__global__ __launch_bounds__(256) void k_part(
    const int* __restrict__ src, const int* __restrict__ dst,
    int* __restrict__ cursor, int* __restrict__ ebuf, int E) {
    __shared__ int sedge[PART_EPB];                    // 8 KB
    __shared__ int h[NBUCK], lofs[NBUCK], gbase[NBUCK], lcur[NBUCK];
    __shared__ int ssc[256];

    int tid = threadIdx.x;
    int eb0 = blockIdx.x * PART_EPB;
    int cnt = min(PART_EPB, E - eb0);

    if (tid < NBUCK) { h[tid] = 0; lcur[tid] = 0; }
    __syncthreads();
    for (int i = tid; i < cnt; i += 256)
        atomicAdd(&h[dst[eb0 + i] / NPB], 1);
    __syncthreads();
    int v = (tid < NBUCK) ? h[tid] : 0;
    ssc[tid] = v;
    __syncthreads();
    for (int off = 1; off < 256; off <<= 1) {
        int val = (tid >= off) ? ssc[tid - off] : 0;
        __syncthreads();
        ssc[tid] += val;
        __syncthreads();
    }
    int excl = ssc[tid] - v;
    if (tid < NBUCK) {
        lofs[tid] = excl;
        gbase[tid] = tid * CAP + atomicAdd(&cursor[tid], v);
    }
    __syncthreads();
    for (int i = tid; i < cnt; i += 256) {
        int s0 = src[eb0 + i];
        int d0 = dst[eb0 + i];
        int b = d0 / NPB;
        int dl = d0 - b * NPB;
        int p = atomicAdd(&lcur[b], 1);
        sedge[lofs[b] + p] = (dl << SRC_BITS) | s0;
    }
    __syncthreads();
    // contiguous run writes; recover bucket by binary search over lofs
    for (int i = tid; i < cnt; i += 256) {
        int lo = 0, hi = NBUCK - 1;
        while (lo < hi) {
            int mid = (lo + hi + 1) >> 1;
            if (lofs[mid] <= i) lo = mid; else hi = mid - 1;
        }
        int pos = gbase[lo] + (i - lofs[lo]);
        if (pos < (lo + 1) * CAP) ebuf[pos] = sedge[i];  // overflow guard
    }
}

// ---------------------- per-bucket CSR build: hist -> scan -> scatter, L2-local
__global__ __launch_bounds__(256) void k_bbuild(
    const int* __restrict__ ebuf, const int* __restrict__ cursor,
    int* __restrict__ row_ptr, int* __restrict__ deg,
    int* __restrict__ col, int N) {
    __shared__ int sdeg[NPB];
    __shared__ int scur[NPB];
    __shared__ int ssum[256];
    int b = blockIdx.x, tid = threadIdx.x;
    int base = b * NPB;
    int nodes = min(NPB, N - base);
    int e0 = b * CAP;
    int e1 = e0 + min(cursor[b], CAP);

    for (int i = tid; i < NPB; i += 256) sdeg[i] = 0;
    __syncthreads();
    for (int e = e0 + tid; e < e1; e += 256)
        atomicAdd(&sdeg[((unsigned)ebuf[e]) >> SRC_BITS], 1);
    __syncthreads();
    int d0 = 0, d1 = 0;
    if (tid < 224) { d0 = sdeg[2 * tid]; d1 = sdeg[2 * tid + 1]; }
    int ts = d0 + d1;
    ssum[tid] = ts;
    __syncthreads();
    for (int off = 1; off < 256; off <<= 1) {
        int val = (tid >= off) ? ssum[tid - off] : 0;
        __syncthreads();
        ssum[tid] += val;
        __syncthreads();
    }
    int excl = ssum[tid] - ts;
    if (tid < 224) {
        scur[2 * tid] = excl;
        scur[2 * tid + 1] = excl + d0;
        if (2 * tid < nodes) {
            row_ptr[base + 2 * tid] = e0 + excl;
            deg[base + 2 * tid] = d0;
        }
        if (2 * tid + 1 < nodes) {
            row_ptr[base + 2 * tid + 1] = e0 + excl + d0;
            deg[base + 2 * tid + 1] = d1;
        }
    }
    __syncthreads();
    for (int e = e0 + tid; e < e1; e += 256) {
        int w = ebuf[e];
        int dl = ((unsigned)w) >> SRC_BITS;
        int p = atomicAdd(&scur[dl], 1);
        col[e0 + p] = w & SRC_MASK;
    }
}

// ------------------------------------------------- MFMA GEMM, W in LDS
// MODE 0 (layer 1): A = x fp32 [N][128] (converted in-register), OC=256,
//                   c<128 -> q1b[N][128] bf16, c>=128 -> p1b[N][128] bf16
// MODE 1 (layer 2): A = hb bf16 [N][128], OC=128,
//                   c<64 -> q2[N][64] bf16, c>=64 -> p2[N][64] fp32
// W staged into LDS from fp32 Wl/Wr (cast fused). Row pad +8 shorts.
template <int OC, int MODE>
__global__ __launch_bounds__(256) void k_wgemm(
    const float* __restrict__ Af, const ushort* __restrict__ Ab,
    const float* __restrict__ WlF, const float* __restrict__ WrF,
    ushort* __restrict__ qb, ushort* __restrict__ pbb, float* __restrict__ pbf,
    int N) {
    const int NT = OC / 16;
    const int LDW = 128 + 8;
    __shared__ ushort Wlds[OC * LDW];

    int tid = threadIdx.x;
    // stage + cast W: OC rows x 128 k, 8 floats per thread-chunk
    for (int it = 0; it < OC / 16; it++) {
        int idx = it * 256 + tid;
        int r = idx >> 4, kc = (idx & 15) * 8;
        const float* Wrow = (r < OC / 2) ? (WlF + (size_t)r * 128)
                                         : (WrF + (size_t)(r - OC / 2) * 128);
        float4 w0 = *(const float4*)(Wrow + kc);
        float4 w1 = *(const float4*)(Wrow + kc + 4);
        v8s wv;
        wv[0] = (short)f2b(w0.x); wv[1] = (short)f2b(w0.y);
        wv[2] = (short)f2b(w0.z); wv[3] = (short)f2b(w0.w);
        wv[4] = (short)f2b(w1.x); wv[5] = (short)f2b(w1.y);
        wv[6] = (short)f2b(w1.z); wv[7] = (short)f2b(w1.w);
        *(v8s*)((short*)Wlds + r * LDW + kc) = wv;
    }
    __syncthreads();

    int wave = tid >> 6;
    int lane = tid & 63;
    int m16 = lane & 15;
    int quad = lane >> 4;
    int rowbase = blockIdx.x * 128 + wave * 32;

    v4f acc[2][NT];
#pragma unroll
    for (int mt = 0; mt < 2; mt++)
#pragma unroll
        for (int t = 0; t < NT; t++) acc[mt][t] = {0.f, 0.f, 0.f, 0.f};

    int ar0 = min(rowbase + m16, N - 1);
    int ar1 = min(rowbase + 16 + m16, N - 1);

#pragma unroll
    for (int ks = 0; ks < 4; ks++) {
        int k0 = ks * 32 + quad * 8;
        v8s a0, a1;
        if (MODE == 0) {
            float4 f00 = *(const float4*)(Af + (size_t)ar0 * 128 + k0);
            float4 f01 = *(const float4*)(Af + (size_t)ar0 * 128 + k0 + 4);
            float4 f10 = *(const float4*)(Af + (size_t)ar1 * 128 + k0);
            float4 f11 = *(const float4*)(Af + (size_t)ar1 * 128 + k0 + 4);
            a0[0] = (short)f2b(f00.x); a0[1] = (short)f2b(f00.y);
            a0[2] = (short)f2b(f00.z); a0[3] = (short)f2b(f00.w);
            a0[4] = (short)f2b(f01.x); a0[5] = (short)f2b(f01.y);
            a0[6] = (short)f2b(f01.z); a0[7] = (short)f2b(f01.w);
            a1[0] = (short)f2b(f10.x); a1[1] = (short)f2b(f10.y);
            a1[2] = (short)f2b(f10.z); a1[3] = (short)f2b(f10.w);
            a1[4] = (short)f2b(f11.x); a1[5] = (short)f2b(f11.y);
            a1[6] = (short)f2b(f11.z); a1[7] = (short)f2b(f11.w);
        } else {
            a0 = *(const v8s*)((const short*)Ab + (size_t)ar0 * 128 + k0);
            a1 = *(const v8s*)((const short*)Ab + (size_t)ar1 * 128 + k0);
        }
#pragma unroll
        for (int t = 0; t < NT; t++) {
            v8s b = *(const v8s*)((const short*)Wlds + (t * 16 + m16) * LDW + k0);
            acc[0][t] = __builtin_amdgcn_mfma_f32_16x16x32_bf16(a0, b, acc[0][t], 0, 0, 0);
            acc[1][t] = __builtin_amdgcn_mfma_f32_16x16x32_bf16(a1, b, acc[1][t], 0, 0, 0);
        }
    }

    // C/D layout: col = t*16 + m16, row(within tile) = quad*4 + r
#pragma unroll
    for (int mt = 0; mt < 2; mt++) {
        int orow0 = rowbase + mt * 16 + quad * 4;
#pragma unroll
        for (int r = 0; r < 4; r++) {
            int orow = orow0 + r;
            if (orow < N) {
#pragma unroll
                for (int t = 0; t < NT; t++) {
                    int c = t * 16 + m16;
                    float v = acc[mt][t][r];
                    if (MODE == 0) {
                        if (c < 128) qb[(size_t)orow * 128 + c] = f2b(v);
                        else pbb[(size_t)orow * 128 + (c - 128)] = f2b(v);
                    } else {
                        if (c < 64) qb[(size_t)orow * 64 + c] = f2b(v);
                        else pbf[(size_t)orow * 64 + (c - 64)] = v;
                    }
                }
            }
        }
    }
}

// ------------------- layer-1 aggregation: h = ReLU(mean(Q1) + P1 + b1) -> bf16
// q1b[N][128], p1b[N][128] bf16. 1 wave/node; two 32-lane halves, each lane
// loads ushort4 (8B): 32 lanes x 8B = one full 256B row per half per slot.
// 8 slots, explicit named loads hoisted before accumulation => 16 rows in
// flight/wave (compiler canary: VGPR must be >= ~28; VGPR ~12 means the
// scheduler serialized the loads again). Tail: same 8 explicit loads with
// clamped col index + per-slot predicated adds (no serial tail).
__global__ void k_agg1(const int* __restrict__ row_ptr, const int* __restrict__ deg,
                       const int* __restrict__ col, const ushort* __restrict__ q1b,
                       const ushort* __restrict__ p1b, const float* __restrict__ bias,
                       ushort* __restrict__ hb, int N) {
    int node = blockIdx.x * (blockDim.x >> 6) + (threadIdx.x >> 6);
    int lane = threadIdx.x & 63;
    if (node >= N) return;
    int s0 = row_ptr[node];
    int dn = deg[node];
    int s1 = s0 + dn;
    int half = lane >> 5, cl = lane & 31;
    int ch = 4 * cl;                        // 4 channels per lane, 8B loads
    float a0 = 0.f, a1 = 0.f, a2 = 0.f, a3 = 0.f;
    int j = s0;
    for (; j + 16 <= s1; j += 16) {
        int c0 = col[j + half],      c1 = col[j + 2 + half];
        int c2 = col[j + 4 + half],  c3 = col[j + 6 + half];
        int c4 = col[j + 8 + half],  c5 = col[j + 10 + half];
        int c6 = col[j + 12 + half], c7 = col[j + 14 + half];
        v4u v0 = *(const v4u*)(q1b + (size_t)c0 * 128 + ch);
        v4u v1 = *(const v4u*)(q1b + (size_t)c1 * 128 + ch);
        v4u v2 = *(const v4u*)(q1b + (size_t)c2 * 128 + ch);
        v4u v3 = *(const v4u*)(q1b + (size_t)c3 * 128 + ch);
        v4u v4 = *(const v4u*)(q1b + (size_t)c4 * 128 + ch);
        v4u v5 = *(const v4u*)(q1b + (size_t)c5 * 128 + ch);
        v4u v6 = *(const v4u*)(q1b + (size_t)c6 * 128 + ch);
        v4u v7 = *(const v4u*)(q1b + (size_t)c7 * 128 + ch);
        a0 += b2f(v0.x) + b2f(v1.x) + b2f(v2.x) + b2f(v3.x)
            + b2f(v4.x) + b2f(v5.x) + b2f(v6.x) + b2f(v7.x);
        a1 += b2f(v0.y) + b2f(v1.y) + b2f(v2.y) + b2f(v3.y)
            + b2f(v4.y) + b2f(v5.y) + b2f(v6.y) + b2f(v7.y);
        a2 += b2f(v0.z) + b2f(v1.z) + b2f(v2.z) + b2f(v3.z)
            + b2f(v4.z) + b2f(v5.z) + b2f(v6.z) + b2f(v7.z);
        a3 += b2f(v0.w) + b2f(v1.w) + b2f(v2.w) + b2f(v3.w)
            + b2f(v4.w) + b2f(v5.w) + b2f(v6.w) + b2f(v7.w);
    }
    if (j < s1) {                           // tail: <16 edges, predicated
        int i0 = j + half,      i1 = j + 2 + half;
        int i2 = j + 4 + half,  i3 = j + 6 + half;
        int i4 = j + 8 + half,  i5 = j + 10 + half;
        int i6 = j + 12 + half, i7 = j + 14 + half;
        int c0 = col[i0 < s1 ? i0 : s0];
        int c1 = col[i1 < s1 ? i1 : s0];
        int c2 = col[i2 < s1 ? i2 : s0];
        int c3 = col[i3 < s1 ? i3 : s0];
        int c4 = col[i4 < s1 ? i4 : s0];
        int c5 = col[i5 < s1 ? i5 : s0];
        int c6 = col[i6 < s1 ? i6 : s0];
        int c7 = col[i7 < s1 ? i7 : s0];
        v4u v0 = *(const v4u*)(q1b + (size_t)c0 * 128 + ch);
        v4u v1 = *(const v4u*)(q1b + (size_t)c1 * 128 + ch);
        v4u v2 = *(const v4u*)(q1b + (size_t)c2 * 128 + ch);
        v4u v3 = *(const v4u*)(q1b + (size_t)c3 * 128 + ch);
        v4u v4 = *(const v4u*)(q1b + (size_t)c4 * 128 + ch);
        v4u v5 = *(const v4u*)(q1b + (size_t)c5 * 128 + ch);
        v4u v6 = *(const v4u*)(q1b + (size_t)c6 * 128 + ch);
        v4u v7 = *(const v4u*)(q1b + (size_t)c7 * 128 + ch);
        if (i0 < s1) { a0 += b2f(v0.x); a1 += b2f(v0.y); a2 += b2f(v0.z); a3 += b2f(v0.w); }
        if (i1 < s1) { a0 += b2f(v1.x); a1 += b2f(v1.y); a2 += b2f(v1.z); a3 += b2f(v1.w); }
        if (i2 < s1) { a0 += b2f(v2.x); a1 += b2f(v2.y); a2 += b2f(v2.z); a3 += b2f(v2.w); }
        if (i3 < s1) { a0 += b2f(v3.x); a1 += b2f(v3.y); a2 += b2f(v3.z); a3 += b2f(v3.w); }
        if (i4 < s1) { a0 += b2f(v4.x); a1 += b2f(v4.y); a2 += b2f(v4.z); a3 += b2f(v4.w); }
        if (i5 < s1) { a0 += b2f(v5.x); a1 += b2f(v5.y); a2 += b2f(v5.z); a3 += b2f(v5.w); }
        if (i6 < s1) { a0 += b2f(v6.x); a1 += b2f(v6.y); a2 += b2f(v6.z); a3 += b2f(v6.w); }
        if (i7 < s1) { a0 += b2f(v7.x); a1 += b2f(v7.y); a2 += b2f(v7.z); a3 += b2f(v7.w); }
    }
    a0 += __shfl_xor(a0, 32);
    a1 += __shfl_xor(a1, 32);
    a2 += __shfl_xor(a2, 32);
    a3 += __shfl_xor(a3, 32);
    if (half == 0) {
        float inv = (dn > 0) ? 1.0f / (float)dn : 0.0f;
        v4u pb = __builtin_nontemporal_load((const v4u*)(p1b + (size_t)node * 128 + ch));
        float4 bi = *(const float4*)(bias + ch);
        v4u o;
        o.x = f2b(fmaxf(a0 * inv + b2f(pb.x) + bi.x, 0.f));
        o.y = f2b(fmaxf(a1 * inv + b2f(pb.y) + bi.y, 0.f));
        o.z = f2b(fmaxf(a2 * inv + b2f(pb.z) + bi.z, 0.f));
        o.w = f2b(fmaxf(a3 * inv + b2f(pb.w) + bi.w, 0.f));
        *(v4u*)(hb + (size_t)node * 128 + ch) = o;
    }
}

// ------------------- layer-2 aggregation: out = mean(Q2) + P2 + b2 -> fp32
// q2[N][64] bf16 (128B rows), p2[N][64] fp32. 1 wave/node; 32-lane half-waves,
// 4B/lane, 8 slots/half -> 16 rows in flight/wave (proven body); explicit
// predicated tail block (no serial tail); shfl_xor(32) combine.
__global__ void k_agg2(const int* __restrict__ row_ptr, const int* __restrict__ deg,
                       const int* __restrict__ col, const ushort* __restrict__ q2,
                       const float* __restrict__ p2, const float* __restrict__ bias,
                       float* __restrict__ out, int N) {
    int node = blockIdx.x * (blockDim.x >> 6) + (threadIdx.x >> 6);
    int lane = threadIdx.x & 63;
    if (node >= N) return;
    int s0 = row_ptr[node];
    int dn = deg[node];
    int s1 = s0 + dn;
    int half = lane >> 5, cl = lane & 31;
    int ch = 2 * cl;
    float ax = 0.f, ay = 0.f;
    int j = s0;
    for (; j + 16 <= s1; j += 16) {
        int c0 = col[j + half],      c1 = col[j + 2 + half];
        int c2 = col[j + 4 + half],  c3 = col[j + 6 + half];
        int c4 = col[j + 8 + half],  c5 = col[j + 10 + half];
        int c6 = col[j + 12 + half], c7 = col[j + 14 + half];
        ushort2 v0 = *(const ushort2*)(q2 + (size_t)c0 * 64 + ch);
        ushort2 v1 = *(const ushort2*)(q2 + (size_t)c1 * 64 + ch);
        ushort2 v2 = *(const ushort2*)(q2 + (size_t)c2 * 64 + ch);
        ushort2 v3 = *(const ushort2*)(q2 + (size_t)c3 * 64 + ch);
        ushort2 v4 = *(const ushort2*)(q2 + (size_t)c4 * 64 + ch);
        ushort2 v5 = *(const ushort2*)(q2 + (size_t)c5 * 64 + ch);
        ushort2 v6 = *(const ushort2*)(q2 + (size_t)c6 * 64 + ch);
        ushort2 v7 = *(const ushort2*)(q2 + (size_t)c7 * 64 + ch);
        ax += b2f(v0.x) + b2f(v1.x) + b2f(v2.x) + b2f(v3.x)
            + b2f(v4.x) + b2f(v5.x) + b2f(v6.x) + b2f(v7.x);
        ay += b2f(v0.y) + b2f(v1.y) + b2f(v2.y) + b2f(v3.y)
            + b2f(v4.y) + b2f(v5.y) + b2f(v6.y) + b2f(v7.y);
    }
    if (j < s1) {                           // tail: <16 edges, predicated
        int i0 = j + half,      i1 = j + 2 + half;
        int i2 = j + 4 + half,  i3 = j + 6 + half;
        int i4 = j + 8 + half,  i5 = j + 10 + half;
        int i6 = j + 12 + half, i7 = j + 14 + half;
        int c0 = col[i0 < s1 ? i0 : s0];
        int c1 = col[i1 < s1 ? i1 : s0];
        int c2 = col[i2 < s1 ? i2 : s0];
        int c3 = col[i3 < s1 ? i3 : s0];
        int c4 = col[i4 < s1 ? i4 : s0];
        int c5 = col[i5 < s1 ? i5 : s0];
        int c6 = col[i6 < s1 ? i6 : s0];
        int c7 = col[i7 < s1 ? i7 : s0];
        ushort2 v0 = *(const ushort2*)(q2 + (size_t)c0 * 64 + ch);
        ushort2 v1 = *(const ushort2*)(q2 + (size_t)c1 * 64 + ch);
        ushort2 v2 = *(const ushort2*)(q2 + (size_t)c2 * 64 + ch);
        ushort2 v3 = *(const ushort2*)(q2 + (size_t)c3 * 64 + ch);
        ushort2 v4 = *(const ushort2*)(q2 + (size_t)c4 * 64 + ch);
        ushort2 v5 = *(const ushort2*)(q2 + (size_t)c5 * 64 + ch);
        ushort2 v6 = *(const ushort2*)(q2 + (size_t)c6 * 64 + ch);
        ushort2 v7 = *(const ushort2*)(q2 + (size_t)c7 * 64 + ch);
        if (i0 < s1) { ax += b2f(v0.x); ay += b2f(v0.y); }
        if (i1 < s1) { ax += b2f(v1.x); ay += b2f(v1.y); }
        if (i2 < s1) { ax += b2f(v2.x); ay += b2f(v2.y); }
        if (i3 < s1) { ax += b2f(v3.x); ay += b2f(v3.y); }
        if (i4 < s1) { ax += b2f(v4.x); ay += b2f(v4.y); }
        if (i5 < s1) { ax += b2f(v5.x); ay += b2f(v5.y); }
        if (i6 < s1) { ax += b2f(v6.x); ay += b2f(v6.y); }
        if (i7 < s1) { ax += b2f(v7.x); ay += b2f(v7.y); }
    }
    ax += __shfl_xor(ax, 32);
    ay += __shfl_xor(ay, 32);
    if (half == 0) {
        float inv = (dn > 0) ? 1.0f / (float)dn : 0.0f;
        v2f pv = __builtin_nontemporal_load((const v2f*)(p2 + (size_t)node * 64 + ch));
        float2 bi = *(const float2*)(bias + ch);
        float2 o;
        o.x = ax * inv + pv.x + bi.x;
        o.y = ay * inv + pv.y + bi.y;
        *(float2*)(out + (size_t)node * 64 + ch) = o;
    }
}

extern "C" void kernel_launch(void* const* d_in, const int* in_sizes, int n_in,
                              void* d_out, int out_size, void* d_ws, size_t ws_size,
                              hipStream_t stream) {
    const float* x   = (const float*)d_in[0];
    const int* ei    = (const int*)d_in[1];
    const float* Wl1 = (const float*)d_in[2];
    const float* bl1 = (const float*)d_in[3];
    const float* Wr1 = (const float*)d_in[4];
    const float* Wl2 = (const float*)d_in[5];
    const float* bl2 = (const float*)d_in[6];
    const float* Wr2 = (const float*)d_in[7];

    const int N = in_sizes[0] / IN_CH;   // 100000
    const int E = in_sizes[1] / 2;       // 1600000
    const int* src = ei;
    const int* dst = ei + E;

    char* p = (char*)d_ws;
    auto carve = [&](size_t bytes) -> void* {
        void* q = (void*)p;
        p += (bytes + 255) & ~(size_t)255;
        return q;
    };
    int* cursor   = (int*)carve(NBUCK * 4);
    int* ebuf     = (int*)carve((size_t)NBUCK * CAP * 4);
    int* col      = (int*)carve((size_t)NBUCK * CAP * 4);
    int* row_ptr  = (int*)carve((size_t)N * 4);
    int* deg      = (int*)carve((size_t)N * 4);
    ushort* q1b   = (ushort*)carve((size_t)N * 128 * 2);
    ushort* p1b   = (ushort*)carve((size_t)N * 128 * 2);
    ushort* hb    = (ushort*)carve((size_t)N * 128 * 2);
    ushort* q2    = (ushort*)carve((size_t)N * 64 * 2);
    float* p2     = (float*)carve((size_t)N * 64 * 4);
    (void)ws_size; (void)n_in;

    float* out = (float*)d_out;
    (void)out_size;

    // ---- partition + CSR build ----
    (void)hipMemsetAsync(cursor, 0, NBUCK * 4, stream);
    k_part<<<(E + PART_EPB - 1) / PART_EPB, 256, 0, stream>>>(src, dst, cursor, ebuf, E);
    k_bbuild<<<NBUCK, 256, 0, stream>>>(ebuf, cursor, row_ptr, deg, col, N);

    // ---- layer 1: [Q1|P1] = x @ [Wl1;Wr1].T (fp32 A, fused cast);
    //      h = ReLU(mean(Q1)+P1+b1) ----
    k_wgemm<256, 0><<<(N + 127) / 128, 256, 0, stream>>>(
        x, nullptr, Wl1, Wr1, q1b, p1b, nullptr, N);
    k_agg1<<<(N + 3) / 4, 256, 0, stream>>>(row_ptr, deg, col, q1b, p1b, bl1, hb, N);

    // ---- layer 2: [Q2|P2] = hb @ [Wl2;Wr2].T; out = mean(Q2)+P2+b2 ----
    k_wgemm<128, 1><<<(N + 127) / 128, 256, 0, stream>>>(
        nullptr, hb, Wl2, Wr2, q2, nullptr, p2, N);
    k_agg2<<<(N + 3) / 4, 256, 0, stream>>>(row_ptr, deg, col, q2, p2, bl2, out, N);
}